// Round 1
// baseline (1553.072 us; speedup 1.0000x reference)
//
#include <hip/hip_runtime.h>
#include <hip/hip_bf16.h>

constexpr int Bn  = 4;
constexpr int Sn  = 2048;
constexpr int NIN = 1024;
constexpr int Hn  = 8;
constexpr int DKn = 128;
constexpr int NL  = Hn * DKn; // 1024

// ---------------- projection GEMM: out = act(x @ W + b) ----------------
constexpr int BM = 64, BN = 64, BK = 16;

__global__ __launch_bounds__(256) void proj_kernel(
    const float* __restrict__ x,
    const float* __restrict__ Wq, const float* __restrict__ bq,
    const float* __restrict__ Wk, const float* __restrict__ bk,
    float* __restrict__ Qo, float* __restrict__ Ko)
{
    const int zz = blockIdx.z;
    const float* __restrict__ W  = zz ? Wk : Wq;
    const float* __restrict__ bv = zz ? bk : bq;
    float* __restrict__ out = zz ? Ko : Qo;

    const int n0 = blockIdx.x * BN;
    const int m0 = blockIdx.y * BM;
    const int tid = threadIdx.x;
    const int tx = tid & 15, ty = tid >> 4;

    __shared__ float As[BK][BM + 4];   // [k][m], padded so float4 rows stay 16B-aligned
    __shared__ float Bs[BK][BN + 4];

    const int la_m = tid >> 2;         // 0..63
    const int la_k = (tid & 3) * 4;    // 0,4,8,12
    const int lb_k = tid >> 4;         // 0..15
    const int lb_n = (tid & 15) * 4;   // 0..60

    float acc[4][4] = {};

    for (int k0 = 0; k0 < NIN; k0 += BK) {
        float4 a4 = *(const float4*)&x[(size_t)(m0 + la_m) * NIN + k0 + la_k];
        float4 b4 = *(const float4*)&W[(size_t)(k0 + lb_k) * NL + n0 + lb_n];
        __syncthreads();
        As[la_k + 0][la_m] = a4.x;
        As[la_k + 1][la_m] = a4.y;
        As[la_k + 2][la_m] = a4.z;
        As[la_k + 3][la_m] = a4.w;
        *(float4*)&Bs[lb_k][lb_n] = b4;
        __syncthreads();
        #pragma unroll
        for (int kk = 0; kk < BK; ++kk) {
            float4 av  = *(const float4*)&As[kk][ty * 4];
            float4 bvv = *(const float4*)&Bs[kk][tx * 4];
            const float aa[4] = {av.x,  av.y,  av.z,  av.w };
            const float bb[4] = {bvv.x, bvv.y, bvv.z, bvv.w};
            #pragma unroll
            for (int i = 0; i < 4; ++i)
                #pragma unroll
                for (int j = 0; j < 4; ++j)
                    acc[i][j] = fmaf(aa[i], bb[j], acc[i][j]);
        }
    }

    #pragma unroll
    for (int i = 0; i < 4; ++i) {
        const int row = m0 + ty * 4 + i;
        float vv[4];
        #pragma unroll
        for (int j = 0; j < 4; ++j) {
            float v = acc[i][j] + bv[n0 + tx * 4 + j];
            vv[j] = zz ? (1.0f / (1.0f + __expf(-v))) : tanhf(v);
        }
        float4 r; r.x = vv[0]; r.y = vv[1]; r.z = vv[2]; r.w = vv[3];
        *(float4*)&out[(size_t)row * NL + n0 + tx * 4] = r;
    }
}

// ------------- attention: row-softmax + column-sum, no PV, no S^2 in HBM -------------
// Block = (q-tile of 16, h, b). Scores bounded by sqrt(DK)=11.3 -> exp <= 8.2e4,
// row sums <= 1.7e8: safe in f32 WITHOUT max subtraction => single QK^T pass.
// probs tile kept in LDS as bf16 (f16 would overflow at exp≈8e4).
constexpr int QT = 16;

__global__ __launch_bounds__(512, 4) void attn_kernel(
    const float* __restrict__ Q, const float* __restrict__ K,
    float* __restrict__ colsum)
{
    extern __shared__ __hip_bfloat16 probs[];   // [QT][Sn]  = 64 KiB
    __shared__ float lsum[QT];

    const int tid = threadIdx.x;
    const int qt = blockIdx.x, h = blockIdx.y, b = blockIdx.z;
    const int q0 = qt * QT;

    const float* __restrict__ Qbase = Q + ((size_t)(b * Sn + q0)) * NL + h * DKn;
    const float* __restrict__ Kbase = K + ((size_t)b * Sn) * NL + h * DKn;

    if (tid < QT) lsum[tid] = 0.0f;
    __syncthreads();

    // Each thread owns 4 key-columns: c = tid + 512*j
    float acc[4][QT];
    #pragma unroll
    for (int j = 0; j < 4; ++j)
        #pragma unroll
        for (int q = 0; q < QT; ++q) acc[j][q] = 0.0f;

    for (int d = 0; d < DKn; d += 4) {
        float4 kv[4];
        #pragma unroll
        for (int j = 0; j < 4; ++j)
            kv[j] = *(const float4*)(Kbase + (size_t)(tid + 512 * j) * NL + d);
        #pragma unroll
        for (int q = 0; q < QT; ++q) {
            float4 qv = *(const float4*)(Qbase + (size_t)q * NL + d); // uniform: L1 broadcast
            #pragma unroll
            for (int j = 0; j < 4; ++j) {
                acc[j][q] = fmaf(qv.x, kv[j].x, acc[j][q]);
                acc[j][q] = fmaf(qv.y, kv[j].y, acc[j][q]);
                acc[j][q] = fmaf(qv.z, kv[j].z, acc[j][q]);
                acc[j][q] = fmaf(qv.w, kv[j].w, acc[j][q]);
            }
        }
    }

    const float scale = 0.08838834764831845f; // 1/sqrt(128)
    float rsum[QT];
    #pragma unroll
    for (int q = 0; q < QT; ++q) rsum[q] = 0.0f;

    #pragma unroll
    for (int j = 0; j < 4; ++j) {
        const int c = tid + 512 * j;
        #pragma unroll
        for (int q = 0; q < QT; ++q) {
            float p = __expf(acc[j][q] * scale);
            probs[q * Sn + c] = __float2bfloat16(p);
            rsum[q] += p;
        }
    }

    // wave reduce the 16 row-sums, then one atomic per wave
    #pragma unroll
    for (int off = 32; off > 0; off >>= 1) {
        #pragma unroll
        for (int q = 0; q < QT; ++q)
            rsum[q] += __shfl_xor(rsum[q], off, 64);
    }
    if ((tid & 63) == 0) {
        #pragma unroll
        for (int q = 0; q < QT; ++q) atomicAdd(&lsum[q], rsum[q]);
    }
    __syncthreads();
    if (tid < QT) lsum[tid] = 1.0f / lsum[tid];
    __syncthreads();

    // column sums of normalized probs for this q-tile
    float* cs = colsum + ((size_t)(b * Hn + h)) * Sn;
    #pragma unroll
    for (int j = 0; j < 4; ++j) {
        const int c = tid + 512 * j;
        float s2 = 0.0f;
        #pragma unroll
        for (int q = 0; q < QT; ++q)
            s2 = fmaf(__bfloat162float(probs[q * Sn + c]), lsum[q], s2);
        atomicAdd(&cs[c], s2);
    }
}

// ---------------- final: out[b,s] = b_fc + sum_h colsum[b,h,s]/S * w_fc[h] ----------------
__global__ void final_kernel(const float* __restrict__ colsum,
                             const float* __restrict__ w_fc,
                             const float* __restrict__ b_fc,
                             float* __restrict__ out)
{
    const int i = blockIdx.x * 256 + threadIdx.x;
    if (i >= Bn * Sn) return;
    const int b = i / Sn, s = i - b * Sn;
    float accv = b_fc[0];
    #pragma unroll
    for (int h = 0; h < Hn; ++h)
        accv += colsum[((size_t)(b * Hn + h)) * Sn + s] * w_fc[h] * (1.0f / Sn);
    out[i] = accv;
}

extern "C" void kernel_launch(void* const* d_in, const int* in_sizes, int n_in,
                              void* d_out, int out_size, void* d_ws, size_t ws_size,
                              hipStream_t stream)
{
    const float* x    = (const float*)d_in[0];
    const float* Wq   = (const float*)d_in[1];
    const float* bq   = (const float*)d_in[2];
    const float* Wk   = (const float*)d_in[3];
    const float* bk   = (const float*)d_in[4];
    const float* w_fc = (const float*)d_in[5];
    const float* b_fc = (const float*)d_in[6];
    float* out = (float*)d_out;

    // workspace layout: Q (32MB) | K (32MB) | colsum (256KB)
    float* Qp = (float*)d_ws;
    float* Kp = Qp + (size_t)Bn * Sn * NL;
    float* colsum = Kp + (size_t)Bn * Sn * NL;

    hipMemsetAsync(colsum, 0, (size_t)Bn * Hn * Sn * sizeof(float), stream);

    dim3 pgrid(NL / BN, (Bn * Sn) / BM, 2);
    proj_kernel<<<pgrid, 256, 0, stream>>>(x, Wq, bq, Wk, bk, Qp, Kp);

    dim3 agrid(Sn / QT, Hn, Bn);
    attn_kernel<<<agrid, 512, QT * Sn * sizeof(__hip_bfloat16), stream>>>(Qp, Kp, colsum);

    final_kernel<<<(Bn * Sn + 255) / 256, 256, 0, stream>>>(colsum, w_fc, b_fc, out);
}

// Round 2
// 698.377 us; speedup vs baseline: 2.2238x; 2.2238x over previous
//
#include <hip/hip_runtime.h>
#include <hip/hip_bf16.h>

constexpr int Bn  = 4;
constexpr int Sn  = 2048;
constexpr int NIN = 1024;
constexpr int Hn  = 8;
constexpr int DKn = 128;
constexpr int NL  = Hn * DKn; // 1024

typedef __bf16 bf16x8 __attribute__((ext_vector_type(8)));
typedef float  f32x4  __attribute__((ext_vector_type(4)));

__device__ __forceinline__ unsigned short f2bf(float f) {   // RNE f32->bf16 bits
    unsigned u = __builtin_bit_cast(unsigned, f);
    u += 0x7FFFu + ((u >> 16) & 1u);
    return (unsigned short)(u >> 16);
}
__device__ __forceinline__ float bf2f(unsigned short b) {
    unsigned u = ((unsigned)b) << 16;
    return __builtin_bit_cast(float, u);
}

// ---------------- projection GEMM: out = act(x @ W + b), emits bf16 ----------------
// Q path (z=0): tanh -> split hi/lo bf16 (hi+lo carries ~16 mantissa bits for the
// 2-term MFMA in attention). K path (z=1): sigmoid -> single bf16.
constexpr int BM = 64, BN = 64, BK = 16;

__global__ __launch_bounds__(256) void proj_kernel(
    const float* __restrict__ x,
    const float* __restrict__ Wq, const float* __restrict__ bq,
    const float* __restrict__ Wk, const float* __restrict__ bk,
    unsigned short* __restrict__ Qh, unsigned short* __restrict__ Ql,
    unsigned short* __restrict__ Kb)
{
    const int zz = blockIdx.z;
    const float* __restrict__ W  = zz ? Wk : Wq;
    const float* __restrict__ bv = zz ? bk : bq;

    const int n0 = blockIdx.x * BN;
    const int m0 = blockIdx.y * BM;
    const int tid = threadIdx.x;
    const int tx = tid & 15, ty = tid >> 4;

    __shared__ float As[BK][BM + 4];
    __shared__ float Bs[BK][BN + 4];

    const int la_m = tid >> 2;
    const int la_k = (tid & 3) * 4;
    const int lb_k = tid >> 4;
    const int lb_n = (tid & 15) * 4;

    float acc[4][4] = {};

    for (int k0 = 0; k0 < NIN; k0 += BK) {
        float4 a4 = *(const float4*)&x[(size_t)(m0 + la_m) * NIN + k0 + la_k];
        float4 b4 = *(const float4*)&W[(size_t)(k0 + lb_k) * NL + n0 + lb_n];
        __syncthreads();
        As[la_k + 0][la_m] = a4.x;
        As[la_k + 1][la_m] = a4.y;
        As[la_k + 2][la_m] = a4.z;
        As[la_k + 3][la_m] = a4.w;
        *(float4*)&Bs[lb_k][lb_n] = b4;
        __syncthreads();
        #pragma unroll
        for (int kk = 0; kk < BK; ++kk) {
            float4 av  = *(const float4*)&As[kk][ty * 4];
            float4 bvv = *(const float4*)&Bs[kk][tx * 4];
            const float aa[4] = {av.x,  av.y,  av.z,  av.w };
            const float bb[4] = {bvv.x, bvv.y, bvv.z, bvv.w};
            #pragma unroll
            for (int i = 0; i < 4; ++i)
                #pragma unroll
                for (int j = 0; j < 4; ++j)
                    acc[i][j] = fmaf(aa[i], bb[j], acc[i][j]);
        }
    }

    #pragma unroll
    for (int i = 0; i < 4; ++i) {
        const size_t row = m0 + ty * 4 + i;
        const size_t base = row * NL + n0 + tx * 4;
        if (!zz) {
            ushort4 hq, lq;
            unsigned short* hp = &hq.x; unsigned short* lp = &lq.x;
            #pragma unroll
            for (int j = 0; j < 4; ++j) {
                float v = acc[i][j] + bv[n0 + tx * 4 + j];
                float a = tanhf(v);
                unsigned short hb = f2bf(a);
                hp[j] = hb;
                lp[j] = f2bf(a - bf2f(hb));
            }
            *(ushort4*)&Qh[base] = hq;
            *(ushort4*)&Ql[base] = lq;
        } else {
            ushort4 kq; unsigned short* kp = &kq.x;
            #pragma unroll
            for (int j = 0; j < 4; ++j) {
                float v = acc[i][j] + bv[n0 + tx * 4 + j];
                float a = 1.0f / (1.0f + __expf(-v));
                kp[j] = f2bf(a);
            }
            *(ushort4*)&Kb[base] = kq;
        }
    }
}

// ------------- attention via MFMA: row-softmax + column-sum, probs in registers -------------
// Block = (b, h, 32-query tile), 8 waves x 256 keys each. Scores bounded (|z|<=11.3),
// so no max-subtraction pass needed; exp<=8.2e4 fits bf16/f32 fine.
// 2-term MFMA: S = Qhi.K + Qlo.K  (K bf16-rounded; error on pooled output ~1e-7).
__global__ __launch_bounds__(512, 2) void attn_kernel(
    const unsigned short* __restrict__ Qh, const unsigned short* __restrict__ Ql,
    const unsigned short* __restrict__ Kb, float* __restrict__ colsum)
{
    __shared__ float lsum[32];
    const int tid  = threadIdx.x;
    const int wave = tid >> 6, lane = tid & 63;
    const int ln15 = lane & 15, lg = lane >> 4;       // C/D: col(key)=ln15, row(q)=lg*4+r
    const int qt = blockIdx.x, h = blockIdx.y, b = blockIdx.z;
    const int q0 = qt * 32;

    if (tid < 32) lsum[tid] = 0.0f;

    // Q fragments for 2 sub-tiles of 16 queries: A-frag lane l -> row q=(l&15), k=(l>>4)*8+j
    bf16x8 qhf[2][4], qlf[2][4];
    #pragma unroll
    for (int t = 0; t < 2; ++t) {
        const size_t ro = ((size_t)(b * Sn + q0 + t * 16 + ln15)) * NL + h * DKn + lg * 8;
        #pragma unroll
        for (int ks = 0; ks < 4; ++ks) {
            qhf[t][ks] = *(const bf16x8*)(Qh + ro + ks * 32);
            qlf[t][ks] = *(const bf16x8*)(Ql + ro + ks * 32);
        }
    }
    __syncthreads();   // lsum init visible before phase-1 atomics

    const unsigned short* kb0 = Kb + (size_t)b * Sn * NL + h * DKn;
    const int keyw = wave * 256;
    const float scale = 0.08838834764831845f; // 1/sqrt(128)

    float rs[2][4] = {{0,0,0,0},{0,0,0,0}};
    unsigned pp[16][2][2];                    // probs, bf16x2-packed, fully unrolled indexing

    #pragma unroll
    for (int f = 0; f < 16; ++f) {
        // B-frag lane l -> col(key)= (l&15), k=(l>>4)*8+j : 16B contiguous per lane per k-step
        const unsigned short* kr = kb0 + (size_t)(keyw + f * 16 + ln15) * NL + lg * 8;
        bf16x8 k0 = *(const bf16x8*)(kr);
        bf16x8 k1 = *(const bf16x8*)(kr + 32);
        bf16x8 k2 = *(const bf16x8*)(kr + 64);
        bf16x8 k3 = *(const bf16x8*)(kr + 96);
        #pragma unroll
        for (int t = 0; t < 2; ++t) {
            f32x4 acc = {0.f, 0.f, 0.f, 0.f};
            acc = __builtin_amdgcn_mfma_f32_16x16x32_bf16(qhf[t][0], k0, acc, 0, 0, 0);
            acc = __builtin_amdgcn_mfma_f32_16x16x32_bf16(qlf[t][0], k0, acc, 0, 0, 0);
            acc = __builtin_amdgcn_mfma_f32_16x16x32_bf16(qhf[t][1], k1, acc, 0, 0, 0);
            acc = __builtin_amdgcn_mfma_f32_16x16x32_bf16(qlf[t][1], k1, acc, 0, 0, 0);
            acc = __builtin_amdgcn_mfma_f32_16x16x32_bf16(qhf[t][2], k2, acc, 0, 0, 0);
            acc = __builtin_amdgcn_mfma_f32_16x16x32_bf16(qlf[t][2], k2, acc, 0, 0, 0);
            acc = __builtin_amdgcn_mfma_f32_16x16x32_bf16(qhf[t][3], k3, acc, 0, 0, 0);
            acc = __builtin_amdgcn_mfma_f32_16x16x32_bf16(qlf[t][3], k3, acc, 0, 0, 0);
            float p0 = __expf(acc[0] * scale);
            float p1 = __expf(acc[1] * scale);
            float p2 = __expf(acc[2] * scale);
            float p3 = __expf(acc[3] * scale);
            rs[t][0] += p0; rs[t][1] += p1; rs[t][2] += p2; rs[t][3] += p3;
            pp[f][t][0] = (unsigned)f2bf(p0) | ((unsigned)f2bf(p1) << 16);
            pp[f][t][1] = (unsigned)f2bf(p2) | ((unsigned)f2bf(p3) << 16);
        }
    }

    // row-sum reduce: across ln15 (xor 1,2,4,8 within 16-lane groups), then across waves
    #pragma unroll
    for (int t = 0; t < 2; ++t) {
        #pragma unroll
        for (int j = 0; j < 4; ++j) {
            float v = rs[t][j];
            v += __shfl_xor(v, 1); v += __shfl_xor(v, 2);
            v += __shfl_xor(v, 4); v += __shfl_xor(v, 8);
            if (ln15 == 0) atomicAdd(&lsum[t * 16 + lg * 4 + j], v);
        }
    }
    __syncthreads();
    if (tid < 32) lsum[tid] = 1.0f / lsum[tid];
    __syncthreads();

    float rv[2][4];
    #pragma unroll
    for (int t = 0; t < 2; ++t)
        #pragma unroll
        for (int j = 0; j < 4; ++j) rv[t][j] = lsum[t * 16 + lg * 4 + j];

    // column sums of normalized probs: in-lane over 8 q's, cross-lane over lane-groups
    float* cs = colsum + ((size_t)(b * Hn + h)) * Sn;
    #pragma unroll
    for (int f = 0; f < 16; ++f) {
        float c = 0.f;
        #pragma unroll
        for (int t = 0; t < 2; ++t) {
            #pragma unroll
            for (int p = 0; p < 2; ++p) {
                unsigned w = pp[f][t][p];
                c += __builtin_bit_cast(float, w << 16)         * rv[t][2 * p];
                c += __builtin_bit_cast(float, w & 0xFFFF0000u) * rv[t][2 * p + 1];
            }
        }
        c += __shfl_xor(c, 16); c += __shfl_xor(c, 32);
        if (lane < 16) atomicAdd(&cs[keyw + f * 16 + lane], c);
    }
}

// ---------------- final: out[b,s] = b_fc + sum_h colsum[b,h,s]/S * w_fc[h] ----------------
__global__ void final_kernel(const float* __restrict__ colsum,
                             const float* __restrict__ w_fc,
                             const float* __restrict__ b_fc,
                             float* __restrict__ out)
{
    const int i = blockIdx.x * 256 + threadIdx.x;
    if (i >= Bn * Sn) return;
    const int b = i / Sn, s = i - b * Sn;
    float accv = b_fc[0];
    #pragma unroll
    for (int h = 0; h < Hn; ++h)
        accv += colsum[((size_t)(b * Hn + h)) * Sn + s] * w_fc[h] * (1.0f / Sn);
    out[i] = accv;
}

extern "C" void kernel_launch(void* const* d_in, const int* in_sizes, int n_in,
                              void* d_out, int out_size, void* d_ws, size_t ws_size,
                              hipStream_t stream)
{
    const float* x    = (const float*)d_in[0];
    const float* Wq   = (const float*)d_in[1];
    const float* bq   = (const float*)d_in[2];
    const float* Wk   = (const float*)d_in[3];
    const float* bk   = (const float*)d_in[4];
    const float* w_fc = (const float*)d_in[5];
    const float* b_fc = (const float*)d_in[6];
    float* out = (float*)d_out;

    // workspace: Qh | Ql | Kb (16MB each, bf16 bits) | colsum (256KB f32)
    const size_t NE = (size_t)Bn * Sn * NL;
    unsigned short* Qh = (unsigned short*)d_ws;
    unsigned short* Ql = Qh + NE;
    unsigned short* Kb = Ql + NE;
    float* colsum = (float*)(Kb + NE);

    hipMemsetAsync(colsum, 0, (size_t)Bn * Hn * Sn * sizeof(float), stream);

    dim3 pgrid(NL / BN, (Bn * Sn) / BM, 2);
    proj_kernel<<<pgrid, 256, 0, stream>>>(x, Wq, bq, Wk, bk, Qh, Ql, Kb);

    dim3 agrid(Sn / 32, Hn, Bn);
    attn_kernel<<<agrid, 512, 0, stream>>>(Qh, Ql, Kb, colsum);

    final_kernel<<<(Bn * Sn + 255) / 256, 256, 0, stream>>>(colsum, w_fc, b_fc, out);
}

// Round 3
// 413.725 us; speedup vs baseline: 3.7539x; 1.6880x over previous
//
#include <hip/hip_runtime.h>
#include <hip/hip_bf16.h>

constexpr int Bn  = 4;
constexpr int Sn  = 2048;
constexpr int NIN = 1024;
constexpr int Hn  = 8;
constexpr int DKn = 128;
constexpr int NL  = Hn * DKn;      // 1024
constexpr int Mrows = Bn * Sn;     // 8192
constexpr int KTILES = NIN / 32;   // 32

typedef __bf16 bf16x8 __attribute__((ext_vector_type(8)));
typedef float  f32x4  __attribute__((ext_vector_type(4)));

__device__ __forceinline__ unsigned short f2bf(float f) {   // RNE f32->bf16 bits
    unsigned u = __builtin_bit_cast(unsigned, f);
    u += 0x7FFFu + ((u >> 16) & 1u);
    return (unsigned short)(u >> 16);
}
__device__ __forceinline__ unsigned pk2(float lo, float hi) {
    return (unsigned)f2bf(lo) | ((unsigned)f2bf(hi) << 16);
}

__device__ __forceinline__ void stage16(const unsigned short* g, unsigned short* l) {
    __builtin_amdgcn_global_load_lds(
        (const __attribute__((address_space(1))) unsigned int*)g,
        (__attribute__((address_space(3))) unsigned int*)l,
        16, 0, 0);
}

// ---------- convert x (f32 row-major) -> bf16 swizzled K-panels ----------
// A_panel tile (tm, kc): 128 rows x 32 k, 8KB. element (r,k): byte = (r*64 + k*2) ^ ((r&7)<<4)
__global__ void convert_x(const float* __restrict__ x, unsigned short* __restrict__ Ap)
{
    const int gid = blockIdx.x * 256 + threadIdx.x;
    const int e = gid * 8;
    const int row = e >> 10, k = e & 1023;
    const int tm = row >> 7, r = row & 127;
    const int kc = k >> 5, kk = k & 31;
    const float4 v0 = *(const float4*)&x[e];
    const float4 v1 = *(const float4*)&x[e + 4];
    uint4 w;
    w.x = pk2(v0.x, v0.y); w.y = pk2(v0.z, v0.w);
    w.z = pk2(v1.x, v1.y); w.w = pk2(v1.z, v1.w);
    const size_t tile = (size_t)(tm * KTILES + kc) * 8192;
    const int byte = (r * 64 + kk * 2) ^ ((r & 7) << 4);
    *(uint4*)((char*)Ap + tile + byte) = w;
}

// ---------- convert W (f32 [k][n]) -> bf16 transposed swizzled panels ----------
// B_panel tile (tn, kc): 128 cols x 32 k. element (c,k): byte = (c*64 + k*2) ^ ((c&7)<<4)
__global__ void convert_w(const float* __restrict__ Wq, const float* __restrict__ Wk,
                          unsigned short* __restrict__ Bp)
{
    const int tn = blockIdx.x >> 5, kc = blockIdx.x & 31;
    const int t = threadIdx.x;
    const int c = t & 127, kh = (t >> 7) * 16;
    const float* __restrict__ W = (tn < 8) ? Wq : Wk;
    const int ncol = (tn & 7) * 128 + c;
    const int k0 = kc * 32 + kh;
    float v[16];
    #pragma unroll
    for (int j = 0; j < 16; ++j)
        v[j] = W[(size_t)(k0 + j) * NL + ncol];
    uint4 w0, w1;
    w0.x = pk2(v[0], v[1]);  w0.y = pk2(v[2], v[3]);
    w0.z = pk2(v[4], v[5]);  w0.w = pk2(v[6], v[7]);
    w1.x = pk2(v[8], v[9]);  w1.y = pk2(v[10], v[11]);
    w1.z = pk2(v[12], v[13]); w1.w = pk2(v[14], v[15]);
    const size_t tbase = (size_t)blockIdx.x * 8192;
    const int b0 = (c * 64 + kh * 2) ^ ((c & 7) << 4);
    const int b1 = (c * 64 + kh * 2 + 16) ^ ((c & 7) << 4);
    *(uint4*)((char*)Bp + tbase + b0) = w0;
    *(uint4*)((char*)Bp + tbase + b1) = w1;
}

// ---------- fused projection GEMM (bf16 MFMA) + bias + activation -> bf16 Q/K ----------
// C = x @ [Wq | Wk], M=8192, N=2048, K=1024. 128x128 tile, 4 waves of 64x64.
__global__ __launch_bounds__(256) void gemm_kernel(
    const unsigned short* __restrict__ Ap, const unsigned short* __restrict__ Bp,
    const float* __restrict__ bq, const float* __restrict__ bk,
    unsigned short* __restrict__ Qb, unsigned short* __restrict__ Kb)
{
    __shared__ unsigned short Asm[128 * 32];   // 8KB, swizzled
    __shared__ unsigned short Bsm[128 * 32];

    const int tid = threadIdx.x;
    const int wave = tid >> 6, lane = tid & 63;
    const int ln = lane & 15, kg = lane >> 4;
    const int wr = wave >> 1, wc = wave & 1;

    // XCD-aware bijective swizzle (1024 % 8 == 0)
    const int bid = blockIdx.x;
    const int wg = (bid & 7) * 128 + (bid >> 3);
    const int bm = wg >> 4, bn = wg & 15;

    const unsigned short* At = Ap + (size_t)bm * (KTILES * 4096);
    const unsigned short* Bt = Bp + (size_t)bn * (KTILES * 4096);

    f32x4 acc[4][4];
    #pragma unroll
    for (int m = 0; m < 4; ++m)
        #pragma unroll
        for (int n = 0; n < 4; ++n) acc[m][n] = (f32x4){0.f, 0.f, 0.f, 0.f};

    // per-lane LDS byte offsets (swizzle: row&7 == ln&7 since wr*64+m*16 is mult of 8)
    int aoff[4], boff[4];
    #pragma unroll
    for (int m = 0; m < 4; ++m) {
        const int row = wr * 64 + m * 16 + ln;
        aoff[m] = (row * 64 + kg * 16) ^ ((ln & 7) << 4);
        const int col = wc * 64 + m * 16 + ln;
        boff[m] = (col * 64 + kg * 16) ^ ((ln & 7) << 4);
    }

    for (int kc = 0; kc < KTILES; ++kc) {
        __syncthreads();                       // previous tile's ds_reads retired
        const unsigned short* ga = At + kc * 4096;
        const unsigned short* gb = Bt + kc * 4096;
        stage16(ga + tid * 8,        Asm + tid * 8);
        stage16(ga + 2048 + tid * 8, Asm + 2048 + tid * 8);
        stage16(gb + tid * 8,        Bsm + tid * 8);
        stage16(gb + 2048 + tid * 8, Bsm + 2048 + tid * 8);
        __syncthreads();                       // vmcnt(0) drained by compiler

        bf16x8 af[4], bf[4];
        #pragma unroll
        for (int m = 0; m < 4; ++m) af[m] = *(const bf16x8*)((const char*)Asm + aoff[m]);
        #pragma unroll
        for (int n = 0; n < 4; ++n) bf[n] = *(const bf16x8*)((const char*)Bsm + boff[n]);
        #pragma unroll
        for (int m = 0; m < 4; ++m)
            #pragma unroll
            for (int n = 0; n < 4; ++n)
                acc[m][n] = __builtin_amdgcn_mfma_f32_16x16x32_bf16(af[m], bf[n], acc[m][n], 0, 0, 0);
    }

    // epilogue: 4x4 in-register transpose -> bias -> activation -> bf16 8B stores
    const bool isQ = (bn < 8);
    const float* __restrict__ bias = isQ ? bq : bk;
    unsigned short* __restrict__ outp = isQ ? Qb : Kb;
    const int cbase = (isQ ? bn : bn - 8) * 128 + wc * 64 + (ln & ~3);
    float4 b4[4];
    #pragma unroll
    for (int n = 0; n < 4; ++n) b4[n] = *(const float4*)&bias[cbase + n * 16];
    const int i = ln & 3;

    #pragma unroll
    for (int m = 0; m < 4; ++m) {
        const size_t grow = bm * 128 + wr * 64 + m * 16 + kg * 4 + i;
        #pragma unroll
        for (int n = 0; n < 4; ++n) {
            float a0 = acc[m][n][0], a1 = acc[m][n][1], a2 = acc[m][n][2], a3 = acc[m][n][3];
            float t;
            t = __shfl_xor((i & 1) ? a0 : a1, 1); if (i & 1) a0 = t; else a1 = t;
            t = __shfl_xor((i & 1) ? a2 : a3, 1); if (i & 1) a2 = t; else a3 = t;
            t = __shfl_xor((i & 2) ? a0 : a2, 2); if (i & 2) a0 = t; else a2 = t;
            t = __shfl_xor((i & 2) ? a1 : a3, 2); if (i & 2) a1 = t; else a3 = t;
            a0 += b4[n].x; a1 += b4[n].y; a2 += b4[n].z; a3 += b4[n].w;
            float r0, r1, r2, r3;
            if (isQ) { r0 = tanhf(a0); r1 = tanhf(a1); r2 = tanhf(a2); r3 = tanhf(a3); }
            else {
                r0 = 1.0f / (1.0f + __expf(-a0)); r1 = 1.0f / (1.0f + __expf(-a1));
                r2 = 1.0f / (1.0f + __expf(-a2)); r3 = 1.0f / (1.0f + __expf(-a3));
            }
            uint2 w; w.x = pk2(r0, r1); w.y = pk2(r2, r3);
            *(uint2*)&outp[grow * NL + cbase + n * 16] = w;
        }
    }
}

// ---------- attention: MFMA QK^T + softmax row-sums + column-sums ----------
__global__ __launch_bounds__(512, 3) void attn_kernel(
    const unsigned short* __restrict__ Qb,
    const unsigned short* __restrict__ Kb, float* __restrict__ colsum)
{
    __shared__ float lsum[32];
    const int tid  = threadIdx.x;
    const int wave = tid >> 6, lane = tid & 63;
    const int ln15 = lane & 15, lg = lane >> 4;
    const int qt = blockIdx.x, h = blockIdx.y, b = blockIdx.z;
    const int q0 = qt * 32;

    if (tid < 32) lsum[tid] = 0.0f;

    bf16x8 qf[2][4];
    #pragma unroll
    for (int t = 0; t < 2; ++t) {
        const size_t ro = ((size_t)(b * Sn + q0 + t * 16 + ln15)) * NL + h * DKn + lg * 8;
        #pragma unroll
        for (int ks = 0; ks < 4; ++ks)
            qf[t][ks] = *(const bf16x8*)(Qb + ro + ks * 32);
    }
    __syncthreads();

    const unsigned short* kb0 = Kb + (size_t)b * Sn * NL + h * DKn;
    const int keyw = wave * 256;
    const float scale = 0.08838834764831845f;

    float rs[2][4] = {{0,0,0,0},{0,0,0,0}};
    unsigned pp[16][2][2];

    #pragma unroll
    for (int f = 0; f < 16; ++f) {
        const unsigned short* kr = kb0 + (size_t)(keyw + f * 16 + ln15) * NL + lg * 8;
        bf16x8 k0 = *(const bf16x8*)(kr);
        bf16x8 k1 = *(const bf16x8*)(kr + 32);
        bf16x8 k2 = *(const bf16x8*)(kr + 64);
        bf16x8 k3 = *(const bf16x8*)(kr + 96);
        #pragma unroll
        for (int t = 0; t < 2; ++t) {
            f32x4 aA = (f32x4){0.f,0.f,0.f,0.f}, aB = (f32x4){0.f,0.f,0.f,0.f};
            aA = __builtin_amdgcn_mfma_f32_16x16x32_bf16(qf[t][0], k0, aA, 0, 0, 0);
            aB = __builtin_amdgcn_mfma_f32_16x16x32_bf16(qf[t][1], k1, aB, 0, 0, 0);
            aA = __builtin_amdgcn_mfma_f32_16x16x32_bf16(qf[t][2], k2, aA, 0, 0, 0);
            aB = __builtin_amdgcn_mfma_f32_16x16x32_bf16(qf[t][3], k3, aB, 0, 0, 0);
            const f32x4 acc = aA + aB;
            float p0 = __expf(acc[0] * scale);
            float p1 = __expf(acc[1] * scale);
            float p2 = __expf(acc[2] * scale);
            float p3 = __expf(acc[3] * scale);
            rs[t][0] += p0; rs[t][1] += p1; rs[t][2] += p2; rs[t][3] += p3;
            pp[f][t][0] = pk2(p0, p1);
            pp[f][t][1] = pk2(p2, p3);
        }
    }

    #pragma unroll
    for (int t = 0; t < 2; ++t)
        #pragma unroll
        for (int j = 0; j < 4; ++j) {
            float v = rs[t][j];
            v += __shfl_xor(v, 1); v += __shfl_xor(v, 2);
            v += __shfl_xor(v, 4); v += __shfl_xor(v, 8);
            if (ln15 == 0) atomicAdd(&lsum[t * 16 + lg * 4 + j], v);
        }
    __syncthreads();
    if (tid < 32) lsum[tid] = 1.0f / lsum[tid];
    __syncthreads();

    float rv[2][4];
    #pragma unroll
    for (int t = 0; t < 2; ++t)
        #pragma unroll
        for (int j = 0; j < 4; ++j) rv[t][j] = lsum[t * 16 + lg * 4 + j];

    float* cs = colsum + ((size_t)(b * Hn + h)) * Sn;
    #pragma unroll
    for (int f = 0; f < 16; ++f) {
        float c = 0.f;
        #pragma unroll
        for (int t = 0; t < 2; ++t) {
            #pragma unroll
            for (int p = 0; p < 2; ++p) {
                unsigned w = pp[f][t][p];
                c += __builtin_bit_cast(float, w << 16)         * rv[t][2 * p];
                c += __builtin_bit_cast(float, w & 0xFFFF0000u) * rv[t][2 * p + 1];
            }
        }
        c += __shfl_xor(c, 16); c += __shfl_xor(c, 32);
        if (lane < 16) atomicAdd(&cs[keyw + f * 16 + lane], c);
    }
}

// ---------- final reduce ----------
__global__ void final_kernel(const float* __restrict__ colsum,
                             const float* __restrict__ w_fc,
                             const float* __restrict__ b_fc,
                             float* __restrict__ out)
{
    const int idx = blockIdx.x * 256 + threadIdx.x;
    if (idx >= Bn * Sn) return;
    const int b = idx / Sn, s = idx - b * Sn;
    float accv = b_fc[0];
    #pragma unroll
    for (int h = 0; h < Hn; ++h)
        accv += colsum[((size_t)(b * Hn + h)) * Sn + s] * w_fc[h] * (1.0f / Sn);
    out[idx] = accv;
}

extern "C" void kernel_launch(void* const* d_in, const int* in_sizes, int n_in,
                              void* d_out, int out_size, void* d_ws, size_t ws_size,
                              hipStream_t stream)
{
    const float* x    = (const float*)d_in[0];
    const float* Wq   = (const float*)d_in[1];
    const float* bq   = (const float*)d_in[2];
    const float* Wk   = (const float*)d_in[3];
    const float* bk   = (const float*)d_in[4];
    const float* w_fc = (const float*)d_in[5];
    const float* b_fc = (const float*)d_in[6];
    float* out = (float*)d_out;

    // ws: A_panel 16MB | B_panel 4MB | Qb 16MB | Kb 16MB | colsum 256KB
    const size_t NE = (size_t)Mrows * NIN;      // 8.4M
    unsigned short* Ap = (unsigned short*)d_ws;
    unsigned short* Bp = Ap + NE;
    unsigned short* Qb = Bp + (size_t)NIN * 2048;
    unsigned short* Kb = Qb + (size_t)Mrows * NL;
    float* colsum = (float*)(Kb + (size_t)Mrows * NL);

    hipMemsetAsync(colsum, 0, (size_t)Bn * Hn * Sn * sizeof(float), stream);

    convert_x<<<Mrows * NIN / 8 / 256, 256, 0, stream>>>(x, Ap);
    convert_w<<<16 * KTILES, 256, 0, stream>>>(Wq, Wk, Bp);
    gemm_kernel<<<(Mrows / 128) * (2048 / 128), 256, 0, stream>>>(Ap, Bp, bq, bk, Qb, Kb);
    attn_kernel<<<dim3(Sn / 32, Hn, Bn), 512, 0, stream>>>(Qb, Kb, colsum);
    final_kernel<<<(Bn * Sn + 255) / 256, 256, 0, stream>>>(colsum, w_fc, b_fc, out);
}

// Round 4
// 280.850 us; speedup vs baseline: 5.5299x; 1.4731x over previous
//
#include <hip/hip_runtime.h>
#include <hip/hip_bf16.h>

constexpr int Bn  = 4;
constexpr int Sn  = 2048;
constexpr int NIN = 1024;
constexpr int Hn  = 8;
constexpr int DKn = 128;
constexpr int NL  = Hn * DKn;      // 1024
constexpr int Mrows = Bn * Sn;     // 8192
constexpr int KTILES = NIN / 32;   // 32

typedef __bf16 bf16x8 __attribute__((ext_vector_type(8)));
typedef float  f32x4  __attribute__((ext_vector_type(4)));

__device__ __forceinline__ unsigned short f2bf(float f) {   // RNE f32->bf16 bits
    unsigned u = __builtin_bit_cast(unsigned, f);
    u += 0x7FFFu + ((u >> 16) & 1u);
    return (unsigned short)(u >> 16);
}
__device__ __forceinline__ unsigned pk2(float lo, float hi) {
    return (unsigned)f2bf(lo) | ((unsigned)f2bf(hi) << 16);
}

__device__ __forceinline__ void stage16(const unsigned short* g, unsigned short* l) {
    __builtin_amdgcn_global_load_lds(
        (const __attribute__((address_space(1))) unsigned int*)g,
        (__attribute__((address_space(3))) unsigned int*)l,
        16, 0, 0);
}

// ---------- convert x (f32 row-major) -> bf16 swizzled K-panels ----------
__global__ void convert_x(const float* __restrict__ x, unsigned short* __restrict__ Ap)
{
    const int gid = blockIdx.x * 256 + threadIdx.x;
    const int e = gid * 8;
    const int row = e >> 10, k = e & 1023;
    const int tm = row >> 7, r = row & 127;
    const int kc = k >> 5, kk = k & 31;
    const float4 v0 = *(const float4*)&x[e];
    const float4 v1 = *(const float4*)&x[e + 4];
    uint4 w;
    w.x = pk2(v0.x, v0.y); w.y = pk2(v0.z, v0.w);
    w.z = pk2(v1.x, v1.y); w.w = pk2(v1.z, v1.w);
    const size_t tile = (size_t)(tm * KTILES + kc) * 8192;
    const int byte = (r * 64 + kk * 2) ^ ((r & 7) << 4);
    *(uint4*)((char*)Ap + tile + byte) = w;
}

// ---------- convert W (f32 [k][n]) -> bf16 transposed swizzled panels ----------
__global__ void convert_w(const float* __restrict__ Wq, const float* __restrict__ Wk,
                          unsigned short* __restrict__ Bp)
{
    const int tn = blockIdx.x >> 5, kc = blockIdx.x & 31;
    const int t = threadIdx.x;
    const int c = t & 127, kh = (t >> 7) * 16;
    const float* __restrict__ W = (tn < 8) ? Wq : Wk;
    const int ncol = (tn & 7) * 128 + c;
    const int k0 = kc * 32 + kh;
    float v[16];
    #pragma unroll
    for (int j = 0; j < 16; ++j)
        v[j] = W[(size_t)(k0 + j) * NL + ncol];
    uint4 w0, w1;
    w0.x = pk2(v[0], v[1]);  w0.y = pk2(v[2], v[3]);
    w0.z = pk2(v[4], v[5]);  w0.w = pk2(v[6], v[7]);
    w1.x = pk2(v[8], v[9]);  w1.y = pk2(v[10], v[11]);
    w1.z = pk2(v[12], v[13]); w1.w = pk2(v[14], v[15]);
    const size_t tbase = (size_t)blockIdx.x * 8192;
    const int b0 = (c * 64 + kh * 2) ^ ((c & 7) << 4);
    const int b1 = (c * 64 + kh * 2 + 16) ^ ((c & 7) << 4);
    *(uint4*)((char*)Bp + tbase + b0) = w0;
    *(uint4*)((char*)Bp + tbase + b1) = w1;
}

// ---------- fused projection GEMM (bf16 MFMA) + bias + activation -> bf16 Q/K ----------
__global__ __launch_bounds__(256) void gemm_kernel(
    const unsigned short* __restrict__ Ap, const unsigned short* __restrict__ Bp,
    const float* __restrict__ bq, const float* __restrict__ bk,
    unsigned short* __restrict__ Qb, unsigned short* __restrict__ Kb)
{
    __shared__ unsigned short Asm[128 * 32];
    __shared__ unsigned short Bsm[128 * 32];

    const int tid = threadIdx.x;
    const int wave = tid >> 6, lane = tid & 63;
    const int ln = lane & 15, kg = lane >> 4;
    const int wr = wave >> 1, wc = wave & 1;

    const int bid = blockIdx.x;
    const int wg = (bid & 7) * 128 + (bid >> 3);
    const int bm = wg >> 4, bn = wg & 15;

    const unsigned short* At = Ap + (size_t)bm * (KTILES * 4096);
    const unsigned short* Bt = Bp + (size_t)bn * (KTILES * 4096);

    f32x4 acc[4][4];
    #pragma unroll
    for (int m = 0; m < 4; ++m)
        #pragma unroll
        for (int n = 0; n < 4; ++n) acc[m][n] = (f32x4){0.f, 0.f, 0.f, 0.f};

    int aoff[4], boff[4];
    #pragma unroll
    for (int m = 0; m < 4; ++m) {
        const int row = wr * 64 + m * 16 + ln;
        aoff[m] = (row * 64 + kg * 16) ^ ((ln & 7) << 4);
        const int col = wc * 64 + m * 16 + ln;
        boff[m] = (col * 64 + kg * 16) ^ ((ln & 7) << 4);
    }

    for (int kc = 0; kc < KTILES; ++kc) {
        __syncthreads();
        const unsigned short* ga = At + kc * 4096;
        const unsigned short* gb = Bt + kc * 4096;
        stage16(ga + tid * 8,        Asm + tid * 8);
        stage16(ga + 2048 + tid * 8, Asm + 2048 + tid * 8);
        stage16(gb + tid * 8,        Bsm + tid * 8);
        stage16(gb + 2048 + tid * 8, Bsm + 2048 + tid * 8);
        __syncthreads();

        bf16x8 af[4], bfv[4];
        #pragma unroll
        for (int m = 0; m < 4; ++m) af[m] = *(const bf16x8*)((const char*)Asm + aoff[m]);
        #pragma unroll
        for (int n = 0; n < 4; ++n) bfv[n] = *(const bf16x8*)((const char*)Bsm + boff[n]);
        #pragma unroll
        for (int m = 0; m < 4; ++m)
            #pragma unroll
            for (int n = 0; n < 4; ++n)
                acc[m][n] = __builtin_amdgcn_mfma_f32_16x16x32_bf16(af[m], bfv[n], acc[m][n], 0, 0, 0);
    }

    const bool isQ = (bn < 8);
    const float* __restrict__ bias = isQ ? bq : bk;
    unsigned short* __restrict__ outp = isQ ? Qb : Kb;
    const int cbase = (isQ ? bn : bn - 8) * 128 + wc * 64 + (ln & ~3);
    float4 b4[4];
    #pragma unroll
    for (int n = 0; n < 4; ++n) b4[n] = *(const float4*)&bias[cbase + n * 16];
    const int i = ln & 3;

    #pragma unroll
    for (int m = 0; m < 4; ++m) {
        const size_t grow = bm * 128 + wr * 64 + m * 16 + kg * 4 + i;
        #pragma unroll
        for (int n = 0; n < 4; ++n) {
            float a0 = acc[m][n][0], a1 = acc[m][n][1], a2 = acc[m][n][2], a3 = acc[m][n][3];
            float t;
            t = __shfl_xor((i & 1) ? a0 : a1, 1); if (i & 1) a0 = t; else a1 = t;
            t = __shfl_xor((i & 1) ? a2 : a3, 1); if (i & 1) a2 = t; else a3 = t;
            t = __shfl_xor((i & 2) ? a0 : a2, 2); if (i & 2) a0 = t; else a2 = t;
            t = __shfl_xor((i & 2) ? a1 : a3, 2); if (i & 2) a1 = t; else a3 = t;
            a0 += b4[n].x; a1 += b4[n].y; a2 += b4[n].z; a3 += b4[n].w;
            float r0, r1, r2, r3;
            if (isQ) { r0 = tanhf(a0); r1 = tanhf(a1); r2 = tanhf(a2); r3 = tanhf(a3); }
            else {
                r0 = 1.0f / (1.0f + __expf(-a0)); r1 = 1.0f / (1.0f + __expf(-a1));
                r2 = 1.0f / (1.0f + __expf(-a2)); r3 = 1.0f / (1.0f + __expf(-a3));
            }
            uint2 w; w.x = pk2(r0, r1); w.y = pk2(r2, r3);
            *(uint2*)&outp[grow * NL + cbase + n * 16] = w;
        }
    }
}

// ---------- attention: two-pass MFMA QK^T recompute, zero prob storage ----------
// Block = (b, h, 64-query tile), 8 waves x 256 keys. Pass A: scores->exp->row sums.
// Pass B: recompute scores (K re-read hits L2), exp * 1/L -> column sums.
// Scores bounded (|z|<=11.3): no max-subtraction needed.
__global__ __launch_bounds__(512, 2) void attn_kernel(
    const unsigned short* __restrict__ Qb,
    const unsigned short* __restrict__ Kb, float* __restrict__ colsum)
{
    __shared__ float lsum[64];
    const int tid  = threadIdx.x;
    const int wave = tid >> 6, lane = tid & 63;
    const int ln15 = lane & 15, lg = lane >> 4;
    const int qt = blockIdx.x, h = blockIdx.y, b = blockIdx.z;
    const int q0 = qt * 64;

    if (tid < 64) lsum[tid] = 0.0f;

    // Q fragments: 4 sub-tiles of 16 queries. A-frag lane l -> row q=(l&15), k=(l>>4)*8+j
    bf16x8 qf[4][4];
    #pragma unroll
    for (int t = 0; t < 4; ++t) {
        const size_t ro = ((size_t)(b * Sn + q0 + t * 16 + ln15)) * NL + h * DKn + lg * 8;
        #pragma unroll
        for (int ks = 0; ks < 4; ++ks)
            qf[t][ks] = *(const bf16x8*)(Qb + ro + ks * 32);
    }
    __syncthreads();   // lsum init visible

    const unsigned short* kb0 = Kb + (size_t)b * Sn * NL + h * DKn;
    const int keyw = wave * 256;
    const float scale = 0.08838834764831845f; // 1/sqrt(128)

    // ---- pass A: row sums ----
    float rs[4][4];
    #pragma unroll
    for (int t = 0; t < 4; ++t)
        #pragma unroll
        for (int j = 0; j < 4; ++j) rs[t][j] = 0.0f;

    #pragma unroll 4
    for (int f = 0; f < 16; ++f) {
        const unsigned short* kr = kb0 + (size_t)(keyw + f * 16 + ln15) * NL + lg * 8;
        bf16x8 k0 = *(const bf16x8*)(kr);
        bf16x8 k1 = *(const bf16x8*)(kr + 32);
        bf16x8 k2 = *(const bf16x8*)(kr + 64);
        bf16x8 k3 = *(const bf16x8*)(kr + 96);
        #pragma unroll
        for (int t = 0; t < 4; ++t) {
            f32x4 aA = (f32x4){0.f,0.f,0.f,0.f}, aB = (f32x4){0.f,0.f,0.f,0.f};
            aA = __builtin_amdgcn_mfma_f32_16x16x32_bf16(qf[t][0], k0, aA, 0, 0, 0);
            aB = __builtin_amdgcn_mfma_f32_16x16x32_bf16(qf[t][1], k1, aB, 0, 0, 0);
            aA = __builtin_amdgcn_mfma_f32_16x16x32_bf16(qf[t][2], k2, aA, 0, 0, 0);
            aB = __builtin_amdgcn_mfma_f32_16x16x32_bf16(qf[t][3], k3, aB, 0, 0, 0);
            const f32x4 acc = aA + aB;
            rs[t][0] += __expf(acc[0] * scale);
            rs[t][1] += __expf(acc[1] * scale);
            rs[t][2] += __expf(acc[2] * scale);
            rs[t][3] += __expf(acc[3] * scale);
        }
    }

    #pragma unroll
    for (int t = 0; t < 4; ++t)
        #pragma unroll
        for (int j = 0; j < 4; ++j) {
            float v = rs[t][j];
            v += __shfl_xor(v, 1); v += __shfl_xor(v, 2);
            v += __shfl_xor(v, 4); v += __shfl_xor(v, 8);
            if (ln15 == 0) atomicAdd(&lsum[t * 16 + lg * 4 + j], v);
        }
    __syncthreads();
    if (tid < 64) lsum[tid] = 1.0f / lsum[tid];
    __syncthreads();

    float rv[4][4];
    #pragma unroll
    for (int t = 0; t < 4; ++t)
        #pragma unroll
        for (int j = 0; j < 4; ++j) rv[t][j] = lsum[t * 16 + lg * 4 + j];

    // ---- pass B: recompute scores, normalized column sums ----
    float* cs = colsum + ((size_t)(b * Hn + h)) * Sn;
    #pragma unroll 4
    for (int f = 0; f < 16; ++f) {
        const unsigned short* kr = kb0 + (size_t)(keyw + f * 16 + ln15) * NL + lg * 8;
        bf16x8 k0 = *(const bf16x8*)(kr);
        bf16x8 k1 = *(const bf16x8*)(kr + 32);
        bf16x8 k2 = *(const bf16x8*)(kr + 64);
        bf16x8 k3 = *(const bf16x8*)(kr + 96);
        float c = 0.0f;
        #pragma unroll
        for (int t = 0; t < 4; ++t) {
            f32x4 aA = (f32x4){0.f,0.f,0.f,0.f}, aB = (f32x4){0.f,0.f,0.f,0.f};
            aA = __builtin_amdgcn_mfma_f32_16x16x32_bf16(qf[t][0], k0, aA, 0, 0, 0);
            aB = __builtin_amdgcn_mfma_f32_16x16x32_bf16(qf[t][1], k1, aB, 0, 0, 0);
            aA = __builtin_amdgcn_mfma_f32_16x16x32_bf16(qf[t][2], k2, aA, 0, 0, 0);
            aB = __builtin_amdgcn_mfma_f32_16x16x32_bf16(qf[t][3], k3, aB, 0, 0, 0);
            const f32x4 acc = aA + aB;
            c = fmaf(__expf(acc[0] * scale), rv[t][0], c);
            c = fmaf(__expf(acc[1] * scale), rv[t][1], c);
            c = fmaf(__expf(acc[2] * scale), rv[t][2], c);
            c = fmaf(__expf(acc[3] * scale), rv[t][3], c);
        }
        c += __shfl_xor(c, 16); c += __shfl_xor(c, 32);
        if (lane < 16) atomicAdd(&cs[keyw + f * 16 + ln15], c);
    }
}

// ---------- final reduce ----------
__global__ void final_kernel(const float* __restrict__ colsum,
                             const float* __restrict__ w_fc,
                             const float* __restrict__ b_fc,
                             float* __restrict__ out)
{
    const int idx = blockIdx.x * 256 + threadIdx.x;
    if (idx >= Bn * Sn) return;
    const int b = idx / Sn, s = idx - b * Sn;
    float accv = b_fc[0];
    #pragma unroll
    for (int h = 0; h < Hn; ++h)
        accv += colsum[((size_t)(b * Hn + h)) * Sn + s] * w_fc[h] * (1.0f / Sn);
    out[idx] = accv;
}

extern "C" void kernel_launch(void* const* d_in, const int* in_sizes, int n_in,
                              void* d_out, int out_size, void* d_ws, size_t ws_size,
                              hipStream_t stream)
{
    const float* x    = (const float*)d_in[0];
    const float* Wq   = (const float*)d_in[1];
    const float* bq   = (const float*)d_in[2];
    const float* Wk   = (const float*)d_in[3];
    const float* bk   = (const float*)d_in[4];
    const float* w_fc = (const float*)d_in[5];
    const float* b_fc = (const float*)d_in[6];
    float* out = (float*)d_out;

    const size_t NE = (size_t)Mrows * NIN;
    unsigned short* Ap = (unsigned short*)d_ws;
    unsigned short* Bp = Ap + NE;
    unsigned short* Qb = Bp + (size_t)NIN * 2048;
    unsigned short* Kb = Qb + (size_t)Mrows * NL;
    float* colsum = (float*)(Kb + (size_t)Mrows * NL);

    hipMemsetAsync(colsum, 0, (size_t)Bn * Hn * Sn * sizeof(float), stream);

    convert_x<<<Mrows * NIN / 8 / 256, 256, 0, stream>>>(x, Ap);
    convert_w<<<16 * KTILES, 256, 0, stream>>>(Wq, Wk, Bp);
    gemm_kernel<<<(Mrows / 128) * (2048 / 128), 256, 0, stream>>>(Ap, Bp, bq, bk, Qb, Kb);
    attn_kernel<<<dim3(Sn / 64, Hn, Bn), 512, 0, stream>>>(Qb, Kb, colsum);
    final_kernel<<<(Bn * Sn + 255) / 256, 256, 0, stream>>>(colsum, w_fc, b_fc, out);
}